// Round 4
// baseline (770.735 us; speedup 1.0000x reference)
//
#include <hip/hip_runtime.h>

constexpr int IN_DIM  = 256;
constexpr int OUT_DIM = 64;
constexpr int NPB     = 128;          // nodes per bucket (dst >> 7)
constexpr int IPT     = 16;           // edges per thread in part_k

typedef __attribute__((ext_vector_type(8))) short bf16x8;
typedef __attribute__((ext_vector_type(4))) float f32x4;

// ---- W fragment precompute (B-operand of mfma_f32_16x16x32_bf16) -----------
__global__ __launch_bounds__(64) void wfrag_k(const float* __restrict__ W,
                                              bf16x8* __restrict__ fragH,
                                              bf16x8* __restrict__ fragL) {
    const int kt = blockIdx.x >> 2;
    const int nt = blockIdx.x & 3;
    const int l  = threadIdx.x;
    const int col = nt * 16 + (l & 15);
    const int k0  = kt * 32 + (l >> 4) * 8;
    bf16x8 h, lo;
#pragma unroll
    for (int j = 0; j < 8; ++j) {
        float f = W[(size_t)(k0 + j) * OUT_DIM + col];
        unsigned u = __float_as_uint(f);
        h[j] = (short)(u >> 16);
        float r = f - __uint_as_float(u & 0xFFFF0000u);
        lo[j] = (short)(__float_as_uint(r) >> 16);
    }
    fragH[blockIdx.x * 64 + l] = h;
    fragL[blockIdx.x * 64 + l] = lo;
}

// ---- GEMM via bf16 MFMA, split precision; xw stored bf16 -------------------
__global__ __launch_bounds__(256) void gemm_xw(const float* __restrict__ x,
                                               const bf16x8* __restrict__ fragH,
                                               const bf16x8* __restrict__ fragL,
                                               unsigned short* __restrict__ xw,
                                               int N) {
    const int lane = threadIdx.x & 63;
    const int wave = threadIdx.x >> 6;
    const int rowbase = (blockIdx.x * 4 + wave) * 32;
    if (rowbase >= N) return;
    const int rlo = lane & 15;
    const int khi = lane >> 4;

    f32x4 acc[2][4];
#pragma unroll
    for (int t = 0; t < 2; ++t)
#pragma unroll
        for (int nt = 0; nt < 4; ++nt) acc[t][nt] = (f32x4){0.f, 0.f, 0.f, 0.f};

#pragma unroll 1
    for (int kt = 0; kt < 8; ++kt) {
        bf16x8 bh[4], bl[4];
#pragma unroll
        for (int nt = 0; nt < 4; ++nt) {
            bh[nt] = fragH[(kt * 4 + nt) * 64 + lane];
            bl[nt] = fragL[(kt * 4 + nt) * 64 + lane];
        }
#pragma unroll
        for (int t = 0; t < 2; ++t) {
            int row = rowbase + t * 16 + rlo;
            if (row > N - 1) row = N - 1;
            const float4* xp = reinterpret_cast<const float4*>(
                x + (size_t)row * IN_DIM + kt * 32 + khi * 8);
            float4 a0 = xp[0];
            float4 a1 = xp[1];
            float f[8] = {a0.x, a0.y, a0.z, a0.w, a1.x, a1.y, a1.z, a1.w};
            bf16x8 ah, al;
#pragma unroll
            for (int j = 0; j < 8; ++j) {
                unsigned u = __float_as_uint(f[j]);
                ah[j] = (short)(u >> 16);
                float r = f[j] - __uint_as_float(u & 0xFFFF0000u);
                al[j] = (short)(__float_as_uint(r) >> 16);
            }
#pragma unroll
            for (int nt = 0; nt < 4; ++nt) {
                acc[t][nt] = __builtin_amdgcn_mfma_f32_16x16x32_bf16(
                    ah, bh[nt], acc[t][nt], 0, 0, 0);
                acc[t][nt] = __builtin_amdgcn_mfma_f32_16x16x32_bf16(
                    ah, bl[nt], acc[t][nt], 0, 0, 0);
                acc[t][nt] = __builtin_amdgcn_mfma_f32_16x16x32_bf16(
                    al, bh[nt], acc[t][nt], 0, 0, 0);
            }
        }
    }

#pragma unroll
    for (int t = 0; t < 2; ++t)
#pragma unroll
        for (int nt = 0; nt < 4; ++nt)
#pragma unroll
            for (int i = 0; i < 4; ++i) {
                int row = rowbase + t * 16 + khi * 4 + i;
                int col = nt * 16 + rlo;
                if (row < N) {
                    unsigned u = __float_as_uint(acc[t][nt][i]);
                    u += 0x7fffu + ((u >> 16) & 1u);
                    xw[(size_t)row * OUT_DIM + col] = (unsigned short)(u >> 16);
                }
            }
}

// ---- bucket histogram: cnt[b] = #edges with dst>>7 == b --------------------
__global__ __launch_bounds__(256) void histb_k(const int* __restrict__ edst,
                                               int* __restrict__ cnt, int E, int NB) {
    __shared__ int h[1024];
    int t = threadIdx.x;
#pragma unroll
    for (int i = t; i < 1024; i += 256) h[i] = 0;
    __syncthreads();
    for (int e = blockIdx.x * 256 + t; e < E; e += gridDim.x * 256)
        atomicAdd(&h[edst[e] >> 7], 1);
    __syncthreads();
    for (int i = t; i < NB; i += 256)
        if (h[i]) atomicAdd(&cnt[i], h[i]);
}

// ---- exclusive scan of NB (<=1024) bucket counts, one block ----------------
__global__ __launch_bounds__(1024) void scanb_k(const int* __restrict__ cnt,
                                                int* __restrict__ base,
                                                int* __restrict__ cursor,
                                                int NB, int E) {
    __shared__ int s[1024];
    int t = threadIdx.x;
    int v = (t < NB) ? cnt[t] : 0;
    s[t] = v;
    __syncthreads();
#pragma unroll
    for (int o = 1; o < 1024; o <<= 1) {
        int a = (t >= o) ? s[t - o] : 0;
        __syncthreads();
        s[t] += a;
        __syncthreads();
    }
    if (t < NB) { base[t] = s[t] - v; cursor[t] = s[t] - v; }
    if (t == 0) base[NB] = E;
}

// ---- partition: rec[] grouped by bucket; per-block range reservation -------
// rec = { src | (dst&127)<<17 , bits(w) }   (requires N < 2^17)
__global__ __launch_bounds__(256) void part_k(const int* __restrict__ esrc,
                                              const int* __restrict__ edst,
                                              const float* __restrict__ ew,
                                              int* __restrict__ cursor,
                                              int2* __restrict__ rec,
                                              int E, int NB) {
    __shared__ int h[1024];
    __shared__ int bb[1024];
    int t = threadIdx.x;
#pragma unroll
    for (int i = t; i < 1024; i += 256) h[i] = 0;
    __syncthreads();
    const int e0 = blockIdx.x * (256 * IPT);
    int br[IPT];
#pragma unroll
    for (int i = 0; i < IPT; ++i) {
        int e = e0 + i * 256 + t;
        br[i] = -1;
        if (e < E) {
            int b = edst[e] >> 7;
            int r = atomicAdd(&h[b], 1);     // local rank, < 4096
            br[i] = (b << 12) | r;
        }
    }
    __syncthreads();
    for (int i = t; i < NB; i += 256) {
        int c = h[i];
        bb[i] = c ? atomicAdd(&cursor[i], c) : 0;
    }
    __syncthreads();
#pragma unroll
    for (int i = 0; i < IPT; ++i) {
        if (br[i] >= 0) {
            int e = e0 + i * 256 + t;        // reload: L1/L2-hot
            int d = edst[e];
            int b = br[i] >> 12;
            int r = br[i] & 0xFFF;
            rec[bb[b] + r] = make_int2(esrc[e] | ((d & 127) << 17),
                                       __float_as_int(ew[e]));
        }
    }
}

// ---- aggregate: one block per bucket, LDS tile, ds_add_f32, fused ReLU -----
__global__ __launch_bounds__(256) void agg_k(const unsigned short* __restrict__ xw,
                                             const int2* __restrict__ rec,
                                             const int* __restrict__ base,
                                             float* __restrict__ out, int N) {
    __shared__ float tile[NPB * OUT_DIM];    // 32 KB
    const int t = threadIdx.x;
    const int lane = t & 63, wave = t >> 6;
    const int b = blockIdx.x;
#pragma unroll
    for (int i = 0; i < 32; ++i) tile[i * 256 + t] = 0.f;
    __syncthreads();

    const int s = base[b], eEnd = base[b + 1];
    int i = s + wave * 4;
    for (; i + 3 < eEnd; i += 16) {          // 4 waves x 4-deep ILP
        int2 r0 = rec[i + 0];
        int2 r1 = rec[i + 1];
        int2 r2 = rec[i + 2];
        int2 r3 = rec[i + 3];
        float v0 = __uint_as_float((unsigned)xw[(size_t)(r0.x & 0x1FFFF) * 64 + lane] << 16);
        float v1 = __uint_as_float((unsigned)xw[(size_t)(r1.x & 0x1FFFF) * 64 + lane] << 16);
        float v2 = __uint_as_float((unsigned)xw[(size_t)(r2.x & 0x1FFFF) * 64 + lane] << 16);
        float v3 = __uint_as_float((unsigned)xw[(size_t)(r3.x & 0x1FFFF) * 64 + lane] << 16);
        __hip_atomic_fetch_add(&tile[((r0.x >> 17) & 127) * 64 + lane],
                               v0 * __int_as_float(r0.y),
                               __ATOMIC_RELAXED, __HIP_MEMORY_SCOPE_WORKGROUP);
        __hip_atomic_fetch_add(&tile[((r1.x >> 17) & 127) * 64 + lane],
                               v1 * __int_as_float(r1.y),
                               __ATOMIC_RELAXED, __HIP_MEMORY_SCOPE_WORKGROUP);
        __hip_atomic_fetch_add(&tile[((r2.x >> 17) & 127) * 64 + lane],
                               v2 * __int_as_float(r2.y),
                               __ATOMIC_RELAXED, __HIP_MEMORY_SCOPE_WORKGROUP);
        __hip_atomic_fetch_add(&tile[((r3.x >> 17) & 127) * 64 + lane],
                               v3 * __int_as_float(r3.y),
                               __ATOMIC_RELAXED, __HIP_MEMORY_SCOPE_WORKGROUP);
    }
    for (; i < eEnd; ++i) {                  // <=3 per wave
        int2 r = rec[i];
        float v = __uint_as_float((unsigned)xw[(size_t)(r.x & 0x1FFFF) * 64 + lane] << 16);
        __hip_atomic_fetch_add(&tile[((r.x >> 17) & 127) * 64 + lane],
                               v * __int_as_float(r.y),
                               __ATOMIC_RELAXED, __HIP_MEMORY_SCOPE_WORKGROUP);
    }
    __syncthreads();

    const int row0 = b << 7;
    const int maxrow = min(NPB, N - row0);
    const float4* t4 = reinterpret_cast<const float4*>(tile);
    float4* o4 = reinterpret_cast<float4*>(out + (size_t)row0 * OUT_DIM);
#pragma unroll
    for (int q = 0; q < 8; ++q) {
        int idx4 = q * 256 + t;              // 16 float4 per row
        int row = idx4 >> 4;
        if (row < maxrow) {
            float4 v = t4[idx4];
            v.x = fmaxf(v.x, 0.f);
            v.y = fmaxf(v.y, 0.f);
            v.z = fmaxf(v.z, 0.f);
            v.w = fmaxf(v.w, 0.f);
            o4[idx4] = v;
        }
    }
}

extern "C" void kernel_launch(void* const* d_in, const int* in_sizes, int n_in,
                              void* d_out, int out_size, void* d_ws, size_t ws_size,
                              hipStream_t stream) {
    const float* x    = (const float*)d_in[0];
    const float* W    = (const float*)d_in[1];
    const int*   esrc = (const int*)d_in[2];
    const int*   edst = (const int*)d_in[3];
    const float* ew   = (const float*)d_in[4];
    float* out = (float*)d_out;

    const int N  = in_sizes[0] / IN_DIM;     // 100000
    const int E  = in_sizes[2];              // 1600000
    const int NB = (N + NPB - 1) / NPB;      // 782

    char* ws = (char*)d_ws;
    size_t o = 0;
    bf16x8* fragH = (bf16x8*)(ws + o);  o += 32 * 64 * 16;
    bf16x8* fragL = (bf16x8*)(ws + o);  o += 32 * 64 * 16;
    unsigned short* xw = (unsigned short*)(ws + o);
    o += (size_t)N * OUT_DIM * 2;            // 12.8 MB
    int2* rec  = (int2*)(ws + o);       o += (size_t)E * 8;   // 12.8 MB
    int* cnt   = (int*)(ws + o);        o += 1024 * 4;
    int* base  = (int*)(ws + o);        o += 1025 * 4;
    int* cursor = (int*)(ws + o);       o += 1024 * 4;

    hipMemsetAsync(cnt, 0, 1024 * sizeof(int), stream);

    wfrag_k<<<32, 64, 0, stream>>>(W, fragH, fragL);
    gemm_xw<<<(N + 127) / 128, 256, 0, stream>>>(x, fragH, fragL, xw, N);
    histb_k<<<512, 256, 0, stream>>>(edst, cnt, E, NB);
    scanb_k<<<1, 1024, 0, stream>>>(cnt, base, cursor, NB, E);
    part_k <<<(E + 256 * IPT - 1) / (256 * IPT), 256, 0, stream>>>(
        esrc, edst, ew, cursor, rec, E, NB);
    agg_k  <<<NB, 256, 0, stream>>>(xw, rec, base, out, N);
}

// Round 5
// 165.825 us; speedup vs baseline: 4.6479x; 4.6479x over previous
//
#include <hip/hip_runtime.h>

constexpr int IN_DIM  = 256;
constexpr int OUT_DIM = 64;
constexpr int NPB     = 128;          // nodes per bucket (dst >> 7)
constexpr int IPT     = 16;           // edges per thread in part_k

typedef __attribute__((ext_vector_type(8))) short bf16x8;
typedef __attribute__((ext_vector_type(4))) float f32x4;

// ---- W fragment precompute (B-operand of mfma_f32_16x16x32_bf16) -----------
__global__ __launch_bounds__(64) void wfrag_k(const float* __restrict__ W,
                                              bf16x8* __restrict__ fragH,
                                              bf16x8* __restrict__ fragL) {
    const int kt = blockIdx.x >> 2;
    const int nt = blockIdx.x & 3;
    const int l  = threadIdx.x;
    const int col = nt * 16 + (l & 15);
    const int k0  = kt * 32 + (l >> 4) * 8;
    bf16x8 h, lo;
#pragma unroll
    for (int j = 0; j < 8; ++j) {
        float f = W[(size_t)(k0 + j) * OUT_DIM + col];
        unsigned u = __float_as_uint(f);
        h[j] = (short)(u >> 16);
        float r = f - __uint_as_float(u & 0xFFFF0000u);
        lo[j] = (short)(__float_as_uint(r) >> 16);
    }
    fragH[blockIdx.x * 64 + l] = h;
    fragL[blockIdx.x * 64 + l] = lo;
}

// ---- GEMM via bf16 MFMA, split precision; xw stored bf16 -------------------
__global__ __launch_bounds__(256) void gemm_xw(const float* __restrict__ x,
                                               const bf16x8* __restrict__ fragH,
                                               const bf16x8* __restrict__ fragL,
                                               unsigned short* __restrict__ xw,
                                               int N) {
    const int lane = threadIdx.x & 63;
    const int wave = threadIdx.x >> 6;
    const int rowbase = (blockIdx.x * 4 + wave) * 32;
    if (rowbase >= N) return;
    const int rlo = lane & 15;
    const int khi = lane >> 4;

    f32x4 acc[2][4];
#pragma unroll
    for (int t = 0; t < 2; ++t)
#pragma unroll
        for (int nt = 0; nt < 4; ++nt) acc[t][nt] = (f32x4){0.f, 0.f, 0.f, 0.f};

#pragma unroll 1
    for (int kt = 0; kt < 8; ++kt) {
        bf16x8 bh[4], bl[4];
#pragma unroll
        for (int nt = 0; nt < 4; ++nt) {
            bh[nt] = fragH[(kt * 4 + nt) * 64 + lane];
            bl[nt] = fragL[(kt * 4 + nt) * 64 + lane];
        }
#pragma unroll
        for (int t = 0; t < 2; ++t) {
            int row = rowbase + t * 16 + rlo;
            if (row > N - 1) row = N - 1;
            const float4* xp = reinterpret_cast<const float4*>(
                x + (size_t)row * IN_DIM + kt * 32 + khi * 8);
            float4 a0 = xp[0];
            float4 a1 = xp[1];
            float f[8] = {a0.x, a0.y, a0.z, a0.w, a1.x, a1.y, a1.z, a1.w};
            bf16x8 ah, al;
#pragma unroll
            for (int j = 0; j < 8; ++j) {
                unsigned u = __float_as_uint(f[j]);
                ah[j] = (short)(u >> 16);
                float r = f[j] - __uint_as_float(u & 0xFFFF0000u);
                al[j] = (short)(__float_as_uint(r) >> 16);
            }
#pragma unroll
            for (int nt = 0; nt < 4; ++nt) {
                acc[t][nt] = __builtin_amdgcn_mfma_f32_16x16x32_bf16(
                    ah, bh[nt], acc[t][nt], 0, 0, 0);
                acc[t][nt] = __builtin_amdgcn_mfma_f32_16x16x32_bf16(
                    ah, bl[nt], acc[t][nt], 0, 0, 0);
                acc[t][nt] = __builtin_amdgcn_mfma_f32_16x16x32_bf16(
                    al, bh[nt], acc[t][nt], 0, 0, 0);
            }
        }
    }

#pragma unroll
    for (int t = 0; t < 2; ++t)
#pragma unroll
        for (int nt = 0; nt < 4; ++nt)
#pragma unroll
            for (int i = 0; i < 4; ++i) {
                int row = rowbase + t * 16 + khi * 4 + i;
                int col = nt * 16 + rlo;
                if (row < N) {
                    unsigned u = __float_as_uint(acc[t][nt][i]);
                    u += 0x7fffu + ((u >> 16) & 1u);
                    xw[(size_t)row * OUT_DIM + col] = (unsigned short)(u >> 16);
                }
            }
}

// ---- bucket histogram: cnt[b] = #edges with dst>>7 == b --------------------
__global__ __launch_bounds__(256) void histb_k(const int* __restrict__ edst,
                                               int* __restrict__ cnt, int E, int NB) {
    __shared__ int h[1024];
    int t = threadIdx.x;
#pragma unroll
    for (int i = t; i < 1024; i += 256) h[i] = 0;
    __syncthreads();
    for (int e = blockIdx.x * 256 + t; e < E; e += gridDim.x * 256)
        atomicAdd(&h[edst[e] >> 7], 1);
    __syncthreads();
    for (int i = t; i < NB; i += 256)
        if (h[i]) atomicAdd(&cnt[i], h[i]);
}

// ---- exclusive scan of NB (<=1024) bucket counts, one block ----------------
__global__ __launch_bounds__(1024) void scanb_k(const int* __restrict__ cnt,
                                                int* __restrict__ base,
                                                int* __restrict__ cursor,
                                                int NB, int E) {
    __shared__ int s[1024];
    int t = threadIdx.x;
    int v = (t < NB) ? cnt[t] : 0;
    s[t] = v;
    __syncthreads();
#pragma unroll
    for (int o = 1; o < 1024; o <<= 1) {
        int a = (t >= o) ? s[t - o] : 0;
        __syncthreads();
        s[t] += a;
        __syncthreads();
    }
    if (t < NB) { base[t] = s[t] - v; cursor[t] = s[t] - v; }
    if (t == 0) base[NB] = E;
}

// ---- partition: rec[] grouped by bucket; per-block range reservation -------
// rec = { src | (dst&127)<<17 , bits(w) }   (requires N < 2^17)
__global__ __launch_bounds__(256) void part_k(const int* __restrict__ esrc,
                                              const int* __restrict__ edst,
                                              const float* __restrict__ ew,
                                              int* __restrict__ cursor,
                                              int2* __restrict__ rec,
                                              int E, int NB) {
    __shared__ int h[1024];
    __shared__ int bb[1024];
    int t = threadIdx.x;
#pragma unroll
    for (int i = t; i < 1024; i += 256) h[i] = 0;
    __syncthreads();
    const int e0 = blockIdx.x * (256 * IPT);
    int br[IPT];
#pragma unroll
    for (int i = 0; i < IPT; ++i) {
        int e = e0 + i * 256 + t;
        br[i] = -1;
        if (e < E) {
            int b = edst[e] >> 7;
            int r = atomicAdd(&h[b], 1);     // local rank, < 4096
            br[i] = (b << 12) | r;
        }
    }
    __syncthreads();
    for (int i = t; i < NB; i += 256) {
        int c = h[i];
        bb[i] = c ? atomicAdd(&cursor[i], c) : 0;
    }
    __syncthreads();
#pragma unroll
    for (int i = 0; i < IPT; ++i) {
        if (br[i] >= 0) {
            int e = e0 + i * 256 + t;        // reload: L1/L2-hot
            int d = edst[e];
            int b = br[i] >> 12;
            int r = br[i] & 0xFFF;
            rec[bb[b] + r] = make_int2(esrc[e] | ((d & 127) << 17),
                                       __float_as_int(ew[e]));
        }
    }
}

// ---- finalize: per-bucket counting sort -> node-ordered val[] + CSR off[] --
// One block per bucket. All writes land in the bucket's own contiguous
// region (~16KB) -> sequential write-back, no line amplification.
__global__ __launch_bounds__(256) void finalize_k(const int2* __restrict__ rec,
                                                  const int* __restrict__ base,
                                                  int2* __restrict__ val,
                                                  int* __restrict__ off,
                                                  int N, int NB) {
    __shared__ int cnt[NPB];
    __shared__ int sc[NPB];
    __shared__ int cur[NPB];
    const int t = threadIdx.x;
    const int b = blockIdx.x;
    const int s = base[b], e = base[b + 1];

    if (t < NPB) cnt[t] = 0;
    __syncthreads();
    for (int i = s + t; i < e; i += 256)
        atomicAdd(&cnt[(rec[i].x >> 17) & 127], 1);
    __syncthreads();

    // Hillis-Steele inclusive scan over 128 counts
    if (t < NPB) sc[t] = cnt[t];
    __syncthreads();
#pragma unroll
    for (int o = 1; o < NPB; o <<= 1) {
        int a = 0;
        if (t < NPB && t >= o) a = sc[t - o];
        __syncthreads();
        if (t < NPB) sc[t] += a;
        __syncthreads();
    }
    if (t < NPB) {
        int excl = sc[t] - cnt[t];
        cur[t] = excl;
        int node = b * NPB + t;
        if (node < N) off[node] = s + excl;
    }
    if (b == NB - 1 && t == 0) off[N] = e;   // global edge count
    __syncthreads();

    for (int i = s + t; i < e; i += 256) {
        int2 r = rec[i];
        int dl = (r.x >> 17) & 127;
        int slot = s + atomicAdd(&cur[dl], 1);
        val[slot] = make_int2(r.x & 0x1FFFF, r.y);
    }
}

// ---- gather: one wave per dst node, register acc, fused ReLU ---------------
__global__ __launch_bounds__(256) void gather_k(const unsigned short* __restrict__ xw,
                                                const int2* __restrict__ val,
                                                const int* __restrict__ off,
                                                float* __restrict__ out, int N) {
    int d = blockIdx.x * 4 + (threadIdx.x >> 6);
    if (d >= N) return;
    int lane = threadIdx.x & 63;
    int b = off[d], e = off[d + 1];
    float acc = 0.f;
    int i = b;
    for (; i + 4 <= e; i += 4) {
        int2 r0 = val[i + 0];
        int2 r1 = val[i + 1];
        int2 r2 = val[i + 2];
        int2 r3 = val[i + 3];
        float v0 = __uint_as_float((unsigned)xw[(size_t)r0.x * OUT_DIM + lane] << 16);
        float v1 = __uint_as_float((unsigned)xw[(size_t)r1.x * OUT_DIM + lane] << 16);
        float v2 = __uint_as_float((unsigned)xw[(size_t)r2.x * OUT_DIM + lane] << 16);
        float v3 = __uint_as_float((unsigned)xw[(size_t)r3.x * OUT_DIM + lane] << 16);
        acc += __int_as_float(r0.y) * v0;
        acc += __int_as_float(r1.y) * v1;
        acc += __int_as_float(r2.y) * v2;
        acc += __int_as_float(r3.y) * v3;
    }
    for (; i < e; ++i) {
        int2 r = val[i];
        acc += __int_as_float(r.y) *
               __uint_as_float((unsigned)xw[(size_t)r.x * OUT_DIM + lane] << 16);
    }
    out[(size_t)d * OUT_DIM + lane] = fmaxf(acc, 0.f);
}

extern "C" void kernel_launch(void* const* d_in, const int* in_sizes, int n_in,
                              void* d_out, int out_size, void* d_ws, size_t ws_size,
                              hipStream_t stream) {
    const float* x    = (const float*)d_in[0];
    const float* W    = (const float*)d_in[1];
    const int*   esrc = (const int*)d_in[2];
    const int*   edst = (const int*)d_in[3];
    const float* ew   = (const float*)d_in[4];
    float* out = (float*)d_out;

    const int N  = in_sizes[0] / IN_DIM;     // 100000
    const int E  = in_sizes[2];              // 1600000
    const int NB = (N + NPB - 1) / NPB;      // 782

    char* ws = (char*)d_ws;
    size_t o = 0;
    bf16x8* fragH = (bf16x8*)(ws + o);  o += 32 * 64 * 16;
    bf16x8* fragL = (bf16x8*)(ws + o);  o += 32 * 64 * 16;
    unsigned short* xw = (unsigned short*)(ws + o);
    o += (size_t)N * OUT_DIM * 2;            // 12.8 MB
    int2* rec  = (int2*)(ws + o);       o += (size_t)E * 8;   // 12.8 MB
    int2* val  = (int2*)(ws + o);       o += (size_t)E * 8;   // 12.8 MB
    int* cnt   = (int*)(ws + o);        o += 1024 * 4;
    int* base  = (int*)(ws + o);        o += 1025 * 4;
    int* cursor = (int*)(ws + o);       o += 1024 * 4;
    int* off   = (int*)(ws + o);        o += (size_t)(N + 1) * 4;

    hipMemsetAsync(cnt, 0, 1024 * sizeof(int), stream);

    wfrag_k<<<32, 64, 0, stream>>>(W, fragH, fragL);
    gemm_xw<<<(N + 127) / 128, 256, 0, stream>>>(x, fragH, fragL, xw, N);
    histb_k<<<512, 256, 0, stream>>>(edst, cnt, E, NB);
    scanb_k<<<1, 1024, 0, stream>>>(cnt, base, cursor, NB, E);
    part_k <<<(E + 256 * IPT - 1) / (256 * IPT), 256, 0, stream>>>(
        esrc, edst, ew, cursor, rec, E, NB);
    finalize_k<<<NB, 256, 0, stream>>>(rec, base, val, off, N, NB);
    gather_k<<<(N + 3) / 4, 256, 0, stream>>>(xw, val, off, out, N);
}

// Round 6
// 142.621 us; speedup vs baseline: 5.4041x; 1.1627x over previous
//
#include <hip/hip_runtime.h>

constexpr int IN_DIM  = 256;
constexpr int OUT_DIM = 64;
constexpr int NPB     = 128;          // nodes per bucket (dst >> 7)
constexpr int IPT     = 16;           // edges per thread in part_k

typedef __attribute__((ext_vector_type(8))) short bf16x8;
typedef __attribute__((ext_vector_type(4))) float f32x4;

// ---- W fragment precompute (B-operand of mfma_f32_16x16x32_bf16) -----------
__global__ __launch_bounds__(64) void wfrag_k(const float* __restrict__ W,
                                              bf16x8* __restrict__ fragH,
                                              bf16x8* __restrict__ fragL) {
    const int kt = blockIdx.x >> 2;
    const int nt = blockIdx.x & 3;
    const int l  = threadIdx.x;
    const int col = nt * 16 + (l & 15);
    const int k0  = kt * 32 + (l >> 4) * 8;
    bf16x8 h, lo;
#pragma unroll
    for (int j = 0; j < 8; ++j) {
        float f = W[(size_t)(k0 + j) * OUT_DIM + col];
        unsigned u = __float_as_uint(f);
        h[j] = (short)(u >> 16);
        float r = f - __uint_as_float(u & 0xFFFF0000u);
        lo[j] = (short)(__float_as_uint(r) >> 16);
    }
    fragH[blockIdx.x * 64 + l] = h;
    fragL[blockIdx.x * 64 + l] = lo;
}

// ---- GEMM via bf16 MFMA, split precision; xw stored bf16 -------------------
__global__ __launch_bounds__(256) void gemm_xw(const float* __restrict__ x,
                                               const bf16x8* __restrict__ fragH,
                                               const bf16x8* __restrict__ fragL,
                                               unsigned short* __restrict__ xw,
                                               int N) {
    const int lane = threadIdx.x & 63;
    const int wave = threadIdx.x >> 6;
    const int rowbase = (blockIdx.x * 4 + wave) * 32;
    if (rowbase >= N) return;
    const int rlo = lane & 15;
    const int khi = lane >> 4;

    f32x4 acc[2][4];
#pragma unroll
    for (int t = 0; t < 2; ++t)
#pragma unroll
        for (int nt = 0; nt < 4; ++nt) acc[t][nt] = (f32x4){0.f, 0.f, 0.f, 0.f};

#pragma unroll 1
    for (int kt = 0; kt < 8; ++kt) {
        bf16x8 bh[4], bl[4];
#pragma unroll
        for (int nt = 0; nt < 4; ++nt) {
            bh[nt] = fragH[(kt * 4 + nt) * 64 + lane];
            bl[nt] = fragL[(kt * 4 + nt) * 64 + lane];
        }
#pragma unroll
        for (int t = 0; t < 2; ++t) {
            int row = rowbase + t * 16 + rlo;
            if (row > N - 1) row = N - 1;
            const float4* xp = reinterpret_cast<const float4*>(
                x + (size_t)row * IN_DIM + kt * 32 + khi * 8);
            float4 a0 = xp[0];
            float4 a1 = xp[1];
            float f[8] = {a0.x, a0.y, a0.z, a0.w, a1.x, a1.y, a1.z, a1.w};
            bf16x8 ah, al;
#pragma unroll
            for (int j = 0; j < 8; ++j) {
                unsigned u = __float_as_uint(f[j]);
                ah[j] = (short)(u >> 16);
                float r = f[j] - __uint_as_float(u & 0xFFFF0000u);
                al[j] = (short)(__float_as_uint(r) >> 16);
            }
#pragma unroll
            for (int nt = 0; nt < 4; ++nt) {
                acc[t][nt] = __builtin_amdgcn_mfma_f32_16x16x32_bf16(
                    ah, bh[nt], acc[t][nt], 0, 0, 0);
                acc[t][nt] = __builtin_amdgcn_mfma_f32_16x16x32_bf16(
                    ah, bl[nt], acc[t][nt], 0, 0, 0);
                acc[t][nt] = __builtin_amdgcn_mfma_f32_16x16x32_bf16(
                    al, bh[nt], acc[t][nt], 0, 0, 0);
            }
        }
    }

#pragma unroll
    for (int t = 0; t < 2; ++t)
#pragma unroll
        for (int nt = 0; nt < 4; ++nt)
#pragma unroll
            for (int i = 0; i < 4; ++i) {
                int row = rowbase + t * 16 + khi * 4 + i;
                int col = nt * 16 + rlo;
                if (row < N) {
                    unsigned u = __float_as_uint(acc[t][nt][i]);
                    u += 0x7fffu + ((u >> 16) & 1u);
                    xw[(size_t)row * OUT_DIM + col] = (unsigned short)(u >> 16);
                }
            }
}

// ---- bucket histogram: cnt[b] = #edges with dst>>7 == b (int4 loads) -------
__global__ __launch_bounds__(256) void histb_k(const int* __restrict__ edst,
                                               int* __restrict__ cnt, int E, int NB) {
    __shared__ int h[1024];
    int t = threadIdx.x;
#pragma unroll
    for (int i = t; i < 1024; i += 256) h[i] = 0;
    __syncthreads();
    const int n4 = E >> 2;
    for (int i = blockIdx.x * 256 + t; i < n4; i += gridDim.x * 256) {
        int4 d4 = reinterpret_cast<const int4*>(edst)[i];
        atomicAdd(&h[d4.x >> 7], 1);
        atomicAdd(&h[d4.y >> 7], 1);
        atomicAdd(&h[d4.z >> 7], 1);
        atomicAdd(&h[d4.w >> 7], 1);
    }
    if (blockIdx.x == 0)
        for (int e = (n4 << 2) + t; e < E; e += 256)
            atomicAdd(&h[edst[e] >> 7], 1);
    __syncthreads();
    for (int i = t; i < NB; i += 256)
        if (h[i]) atomicAdd(&cnt[i], h[i]);
}

// ---- exclusive scan of NB (<=1024) bucket counts, one block ----------------
__global__ __launch_bounds__(1024) void scanb_k(const int* __restrict__ cnt,
                                                int* __restrict__ base,
                                                int* __restrict__ cursor,
                                                int NB, int E) {
    __shared__ int s[1024];
    int t = threadIdx.x;
    int v = (t < NB) ? cnt[t] : 0;
    s[t] = v;
    __syncthreads();
#pragma unroll
    for (int o = 1; o < 1024; o <<= 1) {
        int a = (t >= o) ? s[t - o] : 0;
        __syncthreads();
        s[t] += a;
        __syncthreads();
    }
    if (t < NB) { base[t] = s[t] - v; cursor[t] = s[t] - v; }
    if (t == 0) base[NB] = E;
}

// ---- partition: rec[] grouped by bucket; per-block range reservation -------
// rec = { src | (dst&127)<<17 , bits(w) }   (requires N < 2^17)
// br pack: b(10b) << 19 | dlow(7b) << 12 | rank(12b)
__global__ __launch_bounds__(256) void part_k(const int* __restrict__ esrc,
                                              const int* __restrict__ edst,
                                              const float* __restrict__ ew,
                                              int* __restrict__ cursor,
                                              int2* __restrict__ rec,
                                              int E, int NB) {
    __shared__ int h[1024];
    __shared__ int bb[1024];
    int t = threadIdx.x;
#pragma unroll
    for (int i = t; i < 1024; i += 256) h[i] = 0;
    __syncthreads();
    const int e0 = blockIdx.x * (256 * IPT);
    int br[IPT];
#pragma unroll
    for (int i = 0; i < IPT; ++i) {
        int e = e0 + i * 256 + t;
        br[i] = -1;
        if (e < E) {
            int d = edst[e];
            int b = d >> 7;
            int r = atomicAdd(&h[b], 1);     // local rank, < 4096
            br[i] = (b << 19) | ((d & 127) << 12) | r;
        }
    }
    __syncthreads();
    for (int i = t; i < NB; i += 256) {
        int c = h[i];
        bb[i] = c ? atomicAdd(&cursor[i], c) : 0;
    }
    __syncthreads();
#pragma unroll
    for (int i = 0; i < IPT; ++i) {
        if (br[i] >= 0) {
            int e = e0 + i * 256 + t;        // esrc/ew first touch here
            int b = br[i] >> 19;
            int dlow = (br[i] >> 12) & 127;
            int r = br[i] & 0xFFF;
            rec[bb[b] + r] = make_int2(esrc[e] | (dlow << 17),
                                       __float_as_int(ew[e]));
        }
    }
}

// ---- finalize: per-bucket counting sort -> node-ordered val[] + CSR off[] --
__global__ __launch_bounds__(256) void finalize_k(const int2* __restrict__ rec,
                                                  const int* __restrict__ base,
                                                  int2* __restrict__ val,
                                                  int* __restrict__ off,
                                                  int N, int NB) {
    __shared__ int cnt[NPB];
    __shared__ int sc[NPB];
    __shared__ int cur[NPB];
    const int t = threadIdx.x;
    const int b = blockIdx.x;
    const int s = base[b], e = base[b + 1];

    if (t < NPB) cnt[t] = 0;
    __syncthreads();
    for (int i = s + t; i < e; i += 256)
        atomicAdd(&cnt[(rec[i].x >> 17) & 127], 1);
    __syncthreads();

    if (t < NPB) sc[t] = cnt[t];
    __syncthreads();
#pragma unroll
    for (int o = 1; o < NPB; o <<= 1) {
        int a = 0;
        if (t < NPB && t >= o) a = sc[t - o];
        __syncthreads();
        if (t < NPB) sc[t] += a;
        __syncthreads();
    }
    if (t < NPB) {
        int excl = sc[t] - cnt[t];
        cur[t] = excl;
        int node = b * NPB + t;
        if (node < N) off[node] = s + excl;
    }
    if (b == NB - 1 && t == 0) off[N] = e;
    __syncthreads();

    for (int i = s + t; i < e; i += 256) {
        int2 r = rec[i];
        int dl = (r.x >> 17) & 127;
        int slot = s + atomicAdd(&cur[dl], 1);
        val[slot] = make_int2(r.x & 0x1FFFF, r.y);
    }
}

// ---- gather v2: wave = 1 node, 8 edges in flight (8 lanes x 16B per edge) --
// group g = lane>>3 handles edge i+g; sub-lane s = lane&7 covers cols
// [s*8, s*8+8) as one int4 (8 bf16). Epilogue: xor-shuffle reduce over g,
// lanes 0..7 store the ReLU'd fp32 row (2 x float4 each).
__global__ __launch_bounds__(256) void gather_k(const unsigned short* __restrict__ xw,
                                                const int2* __restrict__ val,
                                                const int* __restrict__ off,
                                                float* __restrict__ out, int N) {
    int d = blockIdx.x * 4 + (threadIdx.x >> 6);
    if (d >= N) return;
    const int lane = threadIdx.x & 63;
    const int g = lane >> 3, s = lane & 7;
    const int b = off[d], e = off[d + 1];

    float acc[8];
#pragma unroll
    for (int j = 0; j < 8; ++j) acc[j] = 0.f;

    for (int i = b; i < e; i += 8) {
        int idx = i + g;
        int2 r = val[min(idx, e - 1)];
        float w = (idx < e) ? __int_as_float(r.y) : 0.f;
        int4 row = *reinterpret_cast<const int4*>(
            xw + (size_t)r.x * OUT_DIM + s * 8);
        unsigned u0 = (unsigned)row.x, u1 = (unsigned)row.y;
        unsigned u2 = (unsigned)row.z, u3 = (unsigned)row.w;
        acc[0] += w * __uint_as_float(u0 << 16);
        acc[1] += w * __uint_as_float(u0 & 0xFFFF0000u);
        acc[2] += w * __uint_as_float(u1 << 16);
        acc[3] += w * __uint_as_float(u1 & 0xFFFF0000u);
        acc[4] += w * __uint_as_float(u2 << 16);
        acc[5] += w * __uint_as_float(u2 & 0xFFFF0000u);
        acc[6] += w * __uint_as_float(u3 << 16);
        acc[7] += w * __uint_as_float(u3 & 0xFFFF0000u);
    }

#pragma unroll
    for (int m = 8; m < 64; m <<= 1)
#pragma unroll
        for (int j = 0; j < 8; ++j)
            acc[j] += __shfl_xor(acc[j], m);

    if (g == 0) {
        float4 v0 = make_float4(fmaxf(acc[0], 0.f), fmaxf(acc[1], 0.f),
                                fmaxf(acc[2], 0.f), fmaxf(acc[3], 0.f));
        float4 v1 = make_float4(fmaxf(acc[4], 0.f), fmaxf(acc[5], 0.f),
                                fmaxf(acc[6], 0.f), fmaxf(acc[7], 0.f));
        float4* op = reinterpret_cast<float4*>(out + (size_t)d * OUT_DIM + s * 8);
        op[0] = v0;
        op[1] = v1;
    }
}

extern "C" void kernel_launch(void* const* d_in, const int* in_sizes, int n_in,
                              void* d_out, int out_size, void* d_ws, size_t ws_size,
                              hipStream_t stream) {
    const float* x    = (const float*)d_in[0];
    const float* W    = (const float*)d_in[1];
    const int*   esrc = (const int*)d_in[2];
    const int*   edst = (const int*)d_in[3];
    const float* ew   = (const float*)d_in[4];
    float* out = (float*)d_out;

    const int N  = in_sizes[0] / IN_DIM;     // 100000
    const int E  = in_sizes[2];              // 1600000
    const int NB = (N + NPB - 1) / NPB;      // 782

    char* ws = (char*)d_ws;
    size_t o = 0;
    bf16x8* fragH = (bf16x8*)(ws + o);  o += 32 * 64 * 16;
    bf16x8* fragL = (bf16x8*)(ws + o);  o += 32 * 64 * 16;
    unsigned short* xw = (unsigned short*)(ws + o);
    o += (size_t)N * OUT_DIM * 2;            // 12.8 MB
    int2* rec  = (int2*)(ws + o);       o += (size_t)E * 8;   // 12.8 MB
    int2* val  = (int2*)(ws + o);       o += (size_t)E * 8;   // 12.8 MB
    int* cnt   = (int*)(ws + o);        o += 1024 * 4;
    int* base  = (int*)(ws + o);        o += 1025 * 4;
    int* cursor = (int*)(ws + o);       o += 1024 * 4;
    int* off   = (int*)(ws + o);        o += (size_t)(N + 1) * 4;

    hipMemsetAsync(cnt, 0, 1024 * sizeof(int), stream);

    wfrag_k<<<32, 64, 0, stream>>>(W, fragH, fragL);
    gemm_xw<<<(N + 127) / 128, 256, 0, stream>>>(x, fragH, fragL, xw, N);
    histb_k<<<512, 256, 0, stream>>>(edst, cnt, E, NB);
    scanb_k<<<1, 1024, 0, stream>>>(cnt, base, cursor, NB, E);
    part_k <<<(E + 256 * IPT - 1) / (256 * IPT), 256, 0, stream>>>(
        esrc, edst, ew, cursor, rec, E, NB);
    finalize_k<<<NB, 256, 0, stream>>>(rec, base, val, off, N, NB);
    gather_k<<<(N + 3) / 4, 256, 0, stream>>>(xw, val, off, out, N);
}

// Round 7
// 129.639 us; speedup vs baseline: 5.9452x; 1.1001x over previous
//
#include <hip/hip_runtime.h>

constexpr int IN_DIM  = 256;
constexpr int OUT_DIM = 64;
constexpr int NPB     = 128;          // nodes per bucket (dst >> 7)
constexpr int IPT     = 16;           // edges per thread in part_k

typedef __attribute__((ext_vector_type(8))) short bf16x8;
typedef __attribute__((ext_vector_type(4))) float f32x4;

// ---- K1: W fragment precompute + zero cnt[] (replaces hipMemsetAsync) ------
__global__ __launch_bounds__(64) void wfrag_k(const float* __restrict__ W,
                                              bf16x8* __restrict__ fragH,
                                              bf16x8* __restrict__ fragL,
                                              int* __restrict__ cnt) {
    const int gid = blockIdx.x * 64 + threadIdx.x;
    if (gid < 1024) cnt[gid] = 0;               // 32 blocks x 64 >= 1024

    const int kt = blockIdx.x >> 2;
    const int nt = blockIdx.x & 3;
    const int l  = threadIdx.x;
    const int col = nt * 16 + (l & 15);
    const int k0  = kt * 32 + (l >> 4) * 8;
    bf16x8 h, lo;
#pragma unroll
    for (int j = 0; j < 8; ++j) {
        float f = W[(size_t)(k0 + j) * OUT_DIM + col];
        unsigned u = __float_as_uint(f);
        h[j] = (short)(u >> 16);
        float r = f - __uint_as_float(u & 0xFFFF0000u);
        lo[j] = (short)(__float_as_uint(r) >> 16);
    }
    fragH[blockIdx.x * 64 + l] = h;
    fragL[blockIdx.x * 64 + l] = lo;
}

// ---- K2: union kernel — blocks [0,GB) = MFMA GEMM, [GB,GB+HB) = histogram --
__global__ __launch_bounds__(256) void gemm_hist_k(
        const float* __restrict__ x,
        const bf16x8* __restrict__ fragH, const bf16x8* __restrict__ fragL,
        unsigned short* __restrict__ xw,
        const int* __restrict__ edst, int* __restrict__ cnt,
        int N, int E, int GB, int HB) {
    __shared__ int h[1024];
    const int bid = blockIdx.x;

    if (bid >= GB) {                            // ---- histogram role ----
        const int t = threadIdx.x;
        for (int i = t; i < 1024; i += 256) h[i] = 0;
        __syncthreads();
        const int hb = bid - GB;
        const int n4 = E >> 2;
        for (int i = hb * 256 + t; i < n4; i += HB * 256) {
            int4 d4 = reinterpret_cast<const int4*>(edst)[i];
            atomicAdd(&h[d4.x >> 7], 1);
            atomicAdd(&h[d4.y >> 7], 1);
            atomicAdd(&h[d4.z >> 7], 1);
            atomicAdd(&h[d4.w >> 7], 1);
        }
        if (hb == 0)
            for (int e = (n4 << 2) + t; e < E; e += 256)
                atomicAdd(&h[edst[e] >> 7], 1);
        __syncthreads();
        for (int i = t; i < 1024; i += 256)
            if (h[i]) atomicAdd(&cnt[i], h[i]);
        return;
    }

    // ---- GEMM role: xw[N,64] = x @ W via bf16 MFMA, split precision ----
    const int lane = threadIdx.x & 63;
    const int wave = threadIdx.x >> 6;
    const int rowbase = (bid * 4 + wave) * 32;
    if (rowbase >= N) return;
    const int rlo = lane & 15;
    const int khi = lane >> 4;

    f32x4 acc[2][4];
#pragma unroll
    for (int t = 0; t < 2; ++t)
#pragma unroll
        for (int nt = 0; nt < 4; ++nt) acc[t][nt] = (f32x4){0.f, 0.f, 0.f, 0.f};

#pragma unroll 1
    for (int kt = 0; kt < 8; ++kt) {
        bf16x8 bh[4], bl[4];
#pragma unroll
        for (int nt = 0; nt < 4; ++nt) {
            bh[nt] = fragH[(kt * 4 + nt) * 64 + lane];
            bl[nt] = fragL[(kt * 4 + nt) * 64 + lane];
        }
#pragma unroll
        for (int t = 0; t < 2; ++t) {
            int row = rowbase + t * 16 + rlo;
            if (row > N - 1) row = N - 1;
            const float4* xp = reinterpret_cast<const float4*>(
                x + (size_t)row * IN_DIM + kt * 32 + khi * 8);
            float4 a0 = xp[0];
            float4 a1 = xp[1];
            float f[8] = {a0.x, a0.y, a0.z, a0.w, a1.x, a1.y, a1.z, a1.w};
            bf16x8 ah, al;
#pragma unroll
            for (int j = 0; j < 8; ++j) {
                unsigned u = __float_as_uint(f[j]);
                ah[j] = (short)(u >> 16);
                float r = f[j] - __uint_as_float(u & 0xFFFF0000u);
                al[j] = (short)(__float_as_uint(r) >> 16);
            }
#pragma unroll
            for (int nt = 0; nt < 4; ++nt) {
                acc[t][nt] = __builtin_amdgcn_mfma_f32_16x16x32_bf16(
                    ah, bh[nt], acc[t][nt], 0, 0, 0);
                acc[t][nt] = __builtin_amdgcn_mfma_f32_16x16x32_bf16(
                    ah, bl[nt], acc[t][nt], 0, 0, 0);
                acc[t][nt] = __builtin_amdgcn_mfma_f32_16x16x32_bf16(
                    al, bh[nt], acc[t][nt], 0, 0, 0);
            }
        }
    }

#pragma unroll
    for (int t = 0; t < 2; ++t)
#pragma unroll
        for (int nt = 0; nt < 4; ++nt)
#pragma unroll
            for (int i = 0; i < 4; ++i) {
                int row = rowbase + t * 16 + khi * 4 + i;
                int col = nt * 16 + rlo;
                if (row < N) {
                    unsigned u = __float_as_uint(acc[t][nt][i]);
                    u += 0x7fffu + ((u >> 16) & 1u);
                    xw[(size_t)row * OUT_DIM + col] = (unsigned short)(u >> 16);
                }
            }
}

// ---- exclusive scan of NB (<=1024) bucket counts, one block ----------------
__global__ __launch_bounds__(1024) void scanb_k(const int* __restrict__ cnt,
                                                int* __restrict__ base,
                                                int* __restrict__ cursor,
                                                int NB, int E) {
    __shared__ int s[1024];
    int t = threadIdx.x;
    int v = (t < NB) ? cnt[t] : 0;
    s[t] = v;
    __syncthreads();
#pragma unroll
    for (int o = 1; o < 1024; o <<= 1) {
        int a = (t >= o) ? s[t - o] : 0;
        __syncthreads();
        s[t] += a;
        __syncthreads();
    }
    if (t < NB) { base[t] = s[t] - v; cursor[t] = s[t] - v; }
    if (t == 0) base[NB] = E;
}

// ---- partition: rec[] grouped by bucket; per-block range reservation -------
// rec = { src | (dst&127)<<17 , bits(w) }   (requires N < 2^17)
// br pack: b(10b) << 19 | dlow(7b) << 12 | rank(12b)
__global__ __launch_bounds__(256) void part_k(const int* __restrict__ esrc,
                                              const int* __restrict__ edst,
                                              const float* __restrict__ ew,
                                              int* __restrict__ cursor,
                                              int2* __restrict__ rec,
                                              int E, int NB) {
    __shared__ int h[1024];
    __shared__ int bb[1024];
    int t = threadIdx.x;
#pragma unroll
    for (int i = t; i < 1024; i += 256) h[i] = 0;
    __syncthreads();
    const int e0 = blockIdx.x * (256 * IPT);
    int br[IPT];
#pragma unroll
    for (int i = 0; i < IPT; ++i) {
        int e = e0 + i * 256 + t;
        br[i] = -1;
        if (e < E) {
            int d = edst[e];
            int b = d >> 7;
            int r = atomicAdd(&h[b], 1);     // local rank, < 4096
            br[i] = (b << 19) | ((d & 127) << 12) | r;
        }
    }
    __syncthreads();
    for (int i = t; i < NB; i += 256) {
        int c = h[i];
        bb[i] = c ? atomicAdd(&cursor[i], c) : 0;
    }
    __syncthreads();
#pragma unroll
    for (int i = 0; i < IPT; ++i) {
        if (br[i] >= 0) {
            int e = e0 + i * 256 + t;
            int b = br[i] >> 19;
            int dlow = (br[i] >> 12) & 127;
            int r = br[i] & 0xFFF;
            rec[bb[b] + r] = make_int2(esrc[e] | (dlow << 17),
                                       __float_as_int(ew[e]));
        }
    }
}

// ---- finalize: per-bucket counting sort -> node-ordered val[] + CSR off[] --
__global__ __launch_bounds__(256) void finalize_k(const int2* __restrict__ rec,
                                                  const int* __restrict__ base,
                                                  int2* __restrict__ val,
                                                  int* __restrict__ off,
                                                  int N, int NB) {
    __shared__ int cnt[NPB];
    __shared__ int sc[NPB];
    __shared__ int cur[NPB];
    const int t = threadIdx.x;
    const int b = blockIdx.x;
    const int s = base[b], e = base[b + 1];

    if (t < NPB) cnt[t] = 0;
    __syncthreads();
    for (int i = s + t; i < e; i += 256)
        atomicAdd(&cnt[(rec[i].x >> 17) & 127], 1);
    __syncthreads();

    if (t < NPB) sc[t] = cnt[t];
    __syncthreads();
#pragma unroll
    for (int o = 1; o < NPB; o <<= 1) {
        int a = 0;
        if (t < NPB && t >= o) a = sc[t - o];
        __syncthreads();
        if (t < NPB) sc[t] += a;
        __syncthreads();
    }
    if (t < NPB) {
        int excl = sc[t] - cnt[t];
        cur[t] = excl;
        int node = b * NPB + t;
        if (node < N) off[node] = s + excl;
    }
    if (b == NB - 1 && t == 0) off[N] = e;
    __syncthreads();

    for (int i = s + t; i < e; i += 256) {
        int2 r = rec[i];
        int dl = (r.x >> 17) & 127;
        int slot = s + atomicAdd(&cur[dl], 1);
        val[slot] = make_int2(r.x & 0x1FFFF, r.y);
    }
}

// ---- gather v3: wave = 1 node, 16 edges in flight --------------------------
// group g = lane>>3 handles edges i+g and i+g+8; sub-lane s = lane&7 covers
// cols [s*8, s*8+8) as one int4 (8 bf16). Xor-shuffle reduce, fused ReLU.
__global__ __launch_bounds__(256) void gather_k(const unsigned short* __restrict__ xw,
                                                const int2* __restrict__ val,
                                                const int* __restrict__ off,
                                                float* __restrict__ out, int N) {
    int d = blockIdx.x * 4 + (threadIdx.x >> 6);
    if (d >= N) return;
    const int lane = threadIdx.x & 63;
    const int g = lane >> 3, s = lane & 7;
    const int b = off[d], e = off[d + 1];

    float acc[8];
#pragma unroll
    for (int j = 0; j < 8; ++j) acc[j] = 0.f;

    for (int i = b; i < e; i += 16) {
        int idx0 = i + g;
        int idx1 = i + g + 8;
        int2 r0 = val[min(idx0, e - 1)];
        int2 r1 = val[min(idx1, e - 1)];
        float w0 = (idx0 < e) ? __int_as_float(r0.y) : 0.f;
        float w1 = (idx1 < e) ? __int_as_float(r1.y) : 0.f;
        int4 row0 = *reinterpret_cast<const int4*>(
            xw + (size_t)r0.x * OUT_DIM + s * 8);
        int4 row1 = *reinterpret_cast<const int4*>(
            xw + (size_t)r1.x * OUT_DIM + s * 8);
        unsigned a0 = (unsigned)row0.x, a1 = (unsigned)row0.y;
        unsigned a2 = (unsigned)row0.z, a3 = (unsigned)row0.w;
        acc[0] += w0 * __uint_as_float(a0 << 16);
        acc[1] += w0 * __uint_as_float(a0 & 0xFFFF0000u);
        acc[2] += w0 * __uint_as_float(a1 << 16);
        acc[3] += w0 * __uint_as_float(a1 & 0xFFFF0000u);
        acc[4] += w0 * __uint_as_float(a2 << 16);
        acc[5] += w0 * __uint_as_float(a2 & 0xFFFF0000u);
        acc[6] += w0 * __uint_as_float(a3 << 16);
        acc[7] += w0 * __uint_as_float(a3 & 0xFFFF0000u);
        unsigned b0 = (unsigned)row1.x, b1 = (unsigned)row1.y;
        unsigned b2 = (unsigned)row1.z, b3 = (unsigned)row1.w;
        acc[0] += w1 * __uint_as_float(b0 << 16);
        acc[1] += w1 * __uint_as_float(b0 & 0xFFFF0000u);
        acc[2] += w1 * __uint_as_float(b1 << 16);
        acc[3] += w1 * __uint_as_float(b1 & 0xFFFF0000u);
        acc[4] += w1 * __uint_as_float(b2 << 16);
        acc[5] += w1 * __uint_as_float(b2 & 0xFFFF0000u);
        acc[6] += w1 * __uint_as_float(b3 << 16);
        acc[7] += w1 * __uint_as_float(b3 & 0xFFFF0000u);
    }

#pragma unroll
    for (int m = 8; m < 64; m <<= 1)
#pragma unroll
        for (int j = 0; j < 8; ++j)
            acc[j] += __shfl_xor(acc[j], m);

    if (g == 0) {
        float4 v0 = make_float4(fmaxf(acc[0], 0.f), fmaxf(acc[1], 0.f),
                                fmaxf(acc[2], 0.f), fmaxf(acc[3], 0.f));
        float4 v1 = make_float4(fmaxf(acc[4], 0.f), fmaxf(acc[5], 0.f),
                                fmaxf(acc[6], 0.f), fmaxf(acc[7], 0.f));
        float4* op = reinterpret_cast<float4*>(out + (size_t)d * OUT_DIM + s * 8);
        op[0] = v0;
        op[1] = v1;
    }
}

extern "C" void kernel_launch(void* const* d_in, const int* in_sizes, int n_in,
                              void* d_out, int out_size, void* d_ws, size_t ws_size,
                              hipStream_t stream) {
    const float* x    = (const float*)d_in[0];
    const float* W    = (const float*)d_in[1];
    const int*   esrc = (const int*)d_in[2];
    const int*   edst = (const int*)d_in[3];
    const float* ew   = (const float*)d_in[4];
    float* out = (float*)d_out;

    const int N  = in_sizes[0] / IN_DIM;     // 100000
    const int E  = in_sizes[2];              // 1600000
    const int NB = (N + NPB - 1) / NPB;      // 782
    const int GB = (N + 127) / 128;          // gemm blocks = 782
    const int HB = 512;                      // histogram blocks

    char* ws = (char*)d_ws;
    size_t o = 0;
    bf16x8* fragH = (bf16x8*)(ws + o);  o += 32 * 64 * 16;
    bf16x8* fragL = (bf16x8*)(ws + o);  o += 32 * 64 * 16;
    unsigned short* xw = (unsigned short*)(ws + o);
    o += (size_t)N * OUT_DIM * 2;            // 12.8 MB
    int2* rec  = (int2*)(ws + o);       o += (size_t)E * 8;   // 12.8 MB
    int2* val  = (int2*)(ws + o);       o += (size_t)E * 8;   // 12.8 MB
    int* cnt   = (int*)(ws + o);        o += 1024 * 4;
    int* base  = (int*)(ws + o);        o += 1025 * 4;
    int* cursor = (int*)(ws + o);       o += 1024 * 4;
    int* off   = (int*)(ws + o);        o += (size_t)(N + 1) * 4;

    wfrag_k<<<32, 64, 0, stream>>>(W, fragH, fragL, cnt);
    gemm_hist_k<<<GB + HB, 256, 0, stream>>>(x, fragH, fragL, xw, edst, cnt,
                                             N, E, GB, HB);
    scanb_k<<<1, 1024, 0, stream>>>(cnt, base, cursor, NB, E);
    part_k <<<(E + 256 * IPT - 1) / (256 * IPT), 256, 0, stream>>>(
        esrc, edst, ew, cursor, rec, E, NB);
    finalize_k<<<NB, 256, 0, stream>>>(rec, base, val, off, N, NB);
    gather_k<<<(N + 3) / 4, 256, 0, stream>>>(xw, val, off, out, N);
}

// Round 8
// 125.158 us; speedup vs baseline: 6.1581x; 1.0358x over previous
//
#include <hip/hip_runtime.h>

constexpr int IN_DIM  = 256;
constexpr int OUT_DIM = 64;
constexpr int NPB     = 128;          // nodes per bucket (dst >> 7)
constexpr int IPT     = 16;           // edges per thread in part_k

typedef __attribute__((ext_vector_type(8))) short bf16x8;
typedef __attribute__((ext_vector_type(4))) float f32x4;

// ---- K1: W fragment precompute + zero cnt[] (replaces hipMemsetAsync) ------
__global__ __launch_bounds__(64) void wfrag_k(const float* __restrict__ W,
                                              bf16x8* __restrict__ fragH,
                                              bf16x8* __restrict__ fragL,
                                              int* __restrict__ cnt) {
    const int gid = blockIdx.x * 64 + threadIdx.x;
    if (gid < 1024) cnt[gid] = 0;               // 32 blocks x 64 >= 1024

    const int kt = blockIdx.x >> 2;
    const int nt = blockIdx.x & 3;
    const int l  = threadIdx.x;
    const int col = nt * 16 + (l & 15);
    const int k0  = kt * 32 + (l >> 4) * 8;
    bf16x8 h, lo;
#pragma unroll
    for (int j = 0; j < 8; ++j) {
        float f = W[(size_t)(k0 + j) * OUT_DIM + col];
        unsigned u = __float_as_uint(f);
        h[j] = (short)(u >> 16);
        float r = f - __uint_as_float(u & 0xFFFF0000u);
        lo[j] = (short)(__float_as_uint(r) >> 16);
    }
    fragH[blockIdx.x * 64 + l] = h;
    fragL[blockIdx.x * 64 + l] = lo;
}

// ---- K2: union kernel — blocks [0,GB) = MFMA GEMM, [GB,GB+HB) = histogram --
__global__ __launch_bounds__(256) void gemm_hist_k(
        const float* __restrict__ x,
        const bf16x8* __restrict__ fragH, const bf16x8* __restrict__ fragL,
        unsigned short* __restrict__ xw,
        const int* __restrict__ edst, int* __restrict__ cnt,
        int N, int E, int GB, int HB) {
    __shared__ int h[1024];
    const int bid = blockIdx.x;

    if (bid >= GB) {                            // ---- histogram role ----
        const int t = threadIdx.x;
        for (int i = t; i < 1024; i += 256) h[i] = 0;
        __syncthreads();
        const int hb = bid - GB;
        const int n4 = E >> 2;
        for (int i = hb * 256 + t; i < n4; i += HB * 256) {
            int4 d4 = reinterpret_cast<const int4*>(edst)[i];
            atomicAdd(&h[d4.x >> 7], 1);
            atomicAdd(&h[d4.y >> 7], 1);
            atomicAdd(&h[d4.z >> 7], 1);
            atomicAdd(&h[d4.w >> 7], 1);
        }
        if (hb == 0)
            for (int e = (n4 << 2) + t; e < E; e += 256)
                atomicAdd(&h[edst[e] >> 7], 1);
        __syncthreads();
        for (int i = t; i < 1024; i += 256)
            if (h[i]) atomicAdd(&cnt[i], h[i]);
        return;
    }

    // ---- GEMM role: xw[N,64] = x @ W via bf16 MFMA, split precision ----
    // Per kt body: 12 independent loads issued first (8 frag + 4 x), then
    // convert + MFMA; unroll 2 lets kt+1's loads overlap kt's compute.
    const int lane = threadIdx.x & 63;
    const int wave = threadIdx.x >> 6;
    const int rowbase = (bid * 4 + wave) * 32;
    if (rowbase >= N) return;
    const int rlo = lane & 15;
    const int khi = lane >> 4;

    int row0 = rowbase + rlo;            // t=0 row for this lane
    int row1 = rowbase + 16 + rlo;       // t=1 row
    if (row0 > N - 1) row0 = N - 1;      // clamp once (last block only)
    if (row1 > N - 1) row1 = N - 1;
    const float4* xp0 = reinterpret_cast<const float4*>(
        x + (size_t)row0 * IN_DIM + khi * 8);
    const float4* xp1 = reinterpret_cast<const float4*>(
        x + (size_t)row1 * IN_DIM + khi * 8);

    f32x4 acc[2][4];
#pragma unroll
    for (int t = 0; t < 2; ++t)
#pragma unroll
        for (int nt = 0; nt < 4; ++nt) acc[t][nt] = (f32x4){0.f, 0.f, 0.f, 0.f};

#pragma unroll 2
    for (int kt = 0; kt < 8; ++kt) {
        // ---- issue all loads for this kt (independent) ----
        bf16x8 bh[4], bl[4];
#pragma unroll
        for (int nt = 0; nt < 4; ++nt) {
            bh[nt] = fragH[(kt * 4 + nt) * 64 + lane];
            bl[nt] = fragL[(kt * 4 + nt) * 64 + lane];
        }
        float4 a0 = xp0[kt * 8 + 0];     // kt*32 floats = kt*8 float4
        float4 a1 = xp0[kt * 8 + 1];
        float4 b0 = xp1[kt * 8 + 0];
        float4 b1 = xp1[kt * 8 + 1];

        // ---- convert both t-subtiles ----
        float f0[8] = {a0.x, a0.y, a0.z, a0.w, a1.x, a1.y, a1.z, a1.w};
        float f1[8] = {b0.x, b0.y, b0.z, b0.w, b1.x, b1.y, b1.z, b1.w};
        bf16x8 ah0, al0, ah1, al1;
#pragma unroll
        for (int j = 0; j < 8; ++j) {
            unsigned u0 = __float_as_uint(f0[j]);
            ah0[j] = (short)(u0 >> 16);
            float r0 = f0[j] - __uint_as_float(u0 & 0xFFFF0000u);
            al0[j] = (short)(__float_as_uint(r0) >> 16);
            unsigned u1 = __float_as_uint(f1[j]);
            ah1[j] = (short)(u1 >> 16);
            float r1 = f1[j] - __uint_as_float(u1 & 0xFFFF0000u);
            al1[j] = (short)(__float_as_uint(r1) >> 16);
        }

        // ---- MFMA: 3-term split precision, both subtiles ----
#pragma unroll
        for (int nt = 0; nt < 4; ++nt) {
            acc[0][nt] = __builtin_amdgcn_mfma_f32_16x16x32_bf16(
                ah0, bh[nt], acc[0][nt], 0, 0, 0);
            acc[0][nt] = __builtin_amdgcn_mfma_f32_16x16x32_bf16(
                ah0, bl[nt], acc[0][nt], 0, 0, 0);
            acc[0][nt] = __builtin_amdgcn_mfma_f32_16x16x32_bf16(
                al0, bh[nt], acc[0][nt], 0, 0, 0);
            acc[1][nt] = __builtin_amdgcn_mfma_f32_16x16x32_bf16(
                ah1, bh[nt], acc[1][nt], 0, 0, 0);
            acc[1][nt] = __builtin_amdgcn_mfma_f32_16x16x32_bf16(
                ah1, bl[nt], acc[1][nt], 0, 0, 0);
            acc[1][nt] = __builtin_amdgcn_mfma_f32_16x16x32_bf16(
                al1, bh[nt], acc[1][nt], 0, 0, 0);
        }
    }

#pragma unroll
    for (int t = 0; t < 2; ++t)
#pragma unroll
        for (int nt = 0; nt < 4; ++nt)
#pragma unroll
            for (int i = 0; i < 4; ++i) {
                int row = rowbase + t * 16 + khi * 4 + i;
                int col = nt * 16 + rlo;
                if (row < N) {
                    unsigned u = __float_as_uint(acc[t][nt][i]);
                    u += 0x7fffu + ((u >> 16) & 1u);
                    xw[(size_t)row * OUT_DIM + col] = (unsigned short)(u >> 16);
                }
            }
}

// ---- exclusive scan of NB (<=1024) bucket counts, one block ----------------
__global__ __launch_bounds__(1024) void scanb_k(const int* __restrict__ cnt,
                                                int* __restrict__ base,
                                                int* __restrict__ cursor,
                                                int NB, int E) {
    __shared__ int s[1024];
    int t = threadIdx.x;
    int v = (t < NB) ? cnt[t] : 0;
    s[t] = v;
    __syncthreads();
#pragma unroll
    for (int o = 1; o < 1024; o <<= 1) {
        int a = (t >= o) ? s[t - o] : 0;
        __syncthreads();
        s[t] += a;
        __syncthreads();
    }
    if (t < NB) { base[t] = s[t] - v; cursor[t] = s[t] - v; }
    if (t == 0) base[NB] = E;
}

// ---- partition: rec[] grouped by bucket; per-block range reservation -------
// rec = { src | (dst&127)<<17 , bits(w) }   (requires N < 2^17)
// br pack: b(10b) << 19 | dlow(7b) << 12 | rank(12b)
__global__ __launch_bounds__(256) void part_k(const int* __restrict__ esrc,
                                              const int* __restrict__ edst,
                                              const float* __restrict__ ew,
                                              int* __restrict__ cursor,
                                              int2* __restrict__ rec,
                                              int E, int NB) {
    __shared__ int h[1024];
    __shared__ int bb[1024];
    int t = threadIdx.x;
#pragma unroll
    for (int i = t; i < 1024; i += 256) h[i] = 0;
    __syncthreads();
    const int e0 = blockIdx.x * (256 * IPT);
    int br[IPT];
#pragma unroll
    for (int i = 0; i < IPT; ++i) {
        int e = e0 + i * 256 + t;
        br[i] = -1;
        if (e < E) {
            int d = edst[e];
            int b = d >> 7;
            int r = atomicAdd(&h[b], 1);     // local rank, < 4096
            br[i] = (b << 19) | ((d & 127) << 12) | r;
        }
    }
    __syncthreads();
    for (int i = t; i < NB; i += 256) {
        int c = h[i];
        bb[i] = c ? atomicAdd(&cursor[i], c) : 0;
    }
    __syncthreads();
#pragma unroll
    for (int i = 0; i < IPT; ++i) {
        if (br[i] >= 0) {
            int e = e0 + i * 256 + t;
            int b = br[i] >> 19;
            int dlow = (br[i] >> 12) & 127;
            int r = br[i] & 0xFFF;
            rec[bb[b] + r] = make_int2(esrc[e] | (dlow << 17),
                                       __float_as_int(ew[e]));
        }
    }
}

// ---- finalize: per-bucket counting sort -> node-ordered val[] + CSR off[] --
__global__ __launch_bounds__(256) void finalize_k(const int2* __restrict__ rec,
                                                  const int* __restrict__ base,
                                                  int2* __restrict__ val,
                                                  int* __restrict__ off,
                                                  int N, int NB) {
    __shared__ int cnt[NPB];
    __shared__ int sc[NPB];
    __shared__ int cur[NPB];
    const int t = threadIdx.x;
    const int b = blockIdx.x;
    const int s = base[b], e = base[b + 1];

    if (t < NPB) cnt[t] = 0;
    __syncthreads();
    for (int i = s + t; i < e; i += 256)
        atomicAdd(&cnt[(rec[i].x >> 17) & 127], 1);
    __syncthreads();

    if (t < NPB) sc[t] = cnt[t];
    __syncthreads();
#pragma unroll
    for (int o = 1; o < NPB; o <<= 1) {
        int a = 0;
        if (t < NPB && t >= o) a = sc[t - o];
        __syncthreads();
        if (t < NPB) sc[t] += a;
        __syncthreads();
    }
    if (t < NPB) {
        int excl = sc[t] - cnt[t];
        cur[t] = excl;
        int node = b * NPB + t;
        if (node < N) off[node] = s + excl;
    }
    if (b == NB - 1 && t == 0) off[N] = e;
    __syncthreads();

    for (int i = s + t; i < e; i += 256) {
        int2 r = rec[i];
        int dl = (r.x >> 17) & 127;
        int slot = s + atomicAdd(&cur[dl], 1);
        val[slot] = make_int2(r.x & 0x1FFFF, r.y);
    }
}

// ---- gather v3: wave = 1 node, 16 edges in flight --------------------------
__global__ __launch_bounds__(256) void gather_k(const unsigned short* __restrict__ xw,
                                                const int2* __restrict__ val,
                                                const int* __restrict__ off,
                                                float* __restrict__ out, int N) {
    int d = blockIdx.x * 4 + (threadIdx.x >> 6);
    if (d >= N) return;
    const int lane = threadIdx.x & 63;
    const int g = lane >> 3, s = lane & 7;
    const int b = off[d], e = off[d + 1];

    float acc[8];
#pragma unroll
    for (int j = 0; j < 8; ++j) acc[j] = 0.f;

    for (int i = b; i < e; i += 16) {
        int idx0 = i + g;
        int idx1 = i + g + 8;
        int2 r0 = val[min(idx0, e - 1)];
        int2 r1 = val[min(idx1, e - 1)];
        float w0 = (idx0 < e) ? __int_as_float(r0.y) : 0.f;
        float w1 = (idx1 < e) ? __int_as_float(r1.y) : 0.f;
        int4 row0 = *reinterpret_cast<const int4*>(
            xw + (size_t)r0.x * OUT_DIM + s * 8);
        int4 row1 = *reinterpret_cast<const int4*>(
            xw + (size_t)r1.x * OUT_DIM + s * 8);
        unsigned a0 = (unsigned)row0.x, a1 = (unsigned)row0.y;
        unsigned a2 = (unsigned)row0.z, a3 = (unsigned)row0.w;
        acc[0] += w0 * __uint_as_float(a0 << 16);
        acc[1] += w0 * __uint_as_float(a0 & 0xFFFF0000u);
        acc[2] += w0 * __uint_as_float(a1 << 16);
        acc[3] += w0 * __uint_as_float(a1 & 0xFFFF0000u);
        acc[4] += w0 * __uint_as_float(a2 << 16);
        acc[5] += w0 * __uint_as_float(a2 & 0xFFFF0000u);
        acc[6] += w0 * __uint_as_float(a3 << 16);
        acc[7] += w0 * __uint_as_float(a3 & 0xFFFF0000u);
        unsigned b0 = (unsigned)row1.x, b1 = (unsigned)row1.y;
        unsigned b2 = (unsigned)row1.z, b3 = (unsigned)row1.w;
        acc[0] += w1 * __uint_as_float(b0 << 16);
        acc[1] += w1 * __uint_as_float(b0 & 0xFFFF0000u);
        acc[2] += w1 * __uint_as_float(b1 << 16);
        acc[3] += w1 * __uint_as_float(b1 & 0xFFFF0000u);
        acc[4] += w1 * __uint_as_float(b2 << 16);
        acc[5] += w1 * __uint_as_float(b2 & 0xFFFF0000u);
        acc[6] += w1 * __uint_as_float(b3 << 16);
        acc[7] += w1 * __uint_as_float(b3 & 0xFFFF0000u);
    }

#pragma unroll
    for (int m = 8; m < 64; m <<= 1)
#pragma unroll
        for (int j = 0; j < 8; ++j)
            acc[j] += __shfl_xor(acc[j], m);

    if (g == 0) {
        float4 v0 = make_float4(fmaxf(acc[0], 0.f), fmaxf(acc[1], 0.f),
                                fmaxf(acc[2], 0.f), fmaxf(acc[3], 0.f));
        float4 v1 = make_float4(fmaxf(acc[4], 0.f), fmaxf(acc[5], 0.f),
                                fmaxf(acc[6], 0.f), fmaxf(acc[7], 0.f));
        float4* op = reinterpret_cast<float4*>(out + (size_t)d * OUT_DIM + s * 8);
        op[0] = v0;
        op[1] = v1;
    }
}

extern "C" void kernel_launch(void* const* d_in, const int* in_sizes, int n_in,
                              void* d_out, int out_size, void* d_ws, size_t ws_size,
                              hipStream_t stream) {
    const float* x    = (const float*)d_in[0];
    const float* W    = (const float*)d_in[1];
    const int*   esrc = (const int*)d_in[2];
    const int*   edst = (const int*)d_in[3];
    const float* ew   = (const float*)d_in[4];
    float* out = (float*)d_out;

    const int N  = in_sizes[0] / IN_DIM;     // 100000
    const int E  = in_sizes[2];              // 1600000
    const int NB = (N + NPB - 1) / NPB;      // 782
    const int GB = (N + 127) / 128;          // gemm blocks = 782
    const int HB = 512;                      // histogram blocks

    char* ws = (char*)d_ws;
    size_t o = 0;
    bf16x8* fragH = (bf16x8*)(ws + o);  o += 32 * 64 * 16;
    bf16x8* fragL = (bf16x8*)(ws + o);  o += 32 * 64 * 16;
    unsigned short* xw = (unsigned short*)(ws + o);
    o += (size_t)N * OUT_DIM * 2;            // 12.8 MB
    int2* rec  = (int2*)(ws + o);       o += (size_t)E * 8;   // 12.8 MB
    int2* val  = (int2*)(ws + o);       o += (size_t)E * 8;   // 12.8 MB
    int* cnt   = (int*)(ws + o);        o += 1024 * 4;
    int* base  = (int*)(ws + o);        o += 1025 * 4;
    int* cursor = (int*)(ws + o);       o += 1024 * 4;
    int* off   = (int*)(ws + o);        o += (size_t)(N + 1) * 4;

    wfrag_k<<<32, 64, 0, stream>>>(W, fragH, fragL, cnt);
    gemm_hist_k<<<GB + HB, 256, 0, stream>>>(x, fragH, fragL, xw, edst, cnt,
                                             N, E, GB, HB);
    scanb_k<<<1, 1024, 0, stream>>>(cnt, base, cursor, NB, E);
    part_k <<<(E + 256 * IPT - 1) / (256 * IPT), 256, 0, stream>>>(
        esrc, edst, ew, cursor, rec, E, NB);
    finalize_k<<<NB, 256, 0, stream>>>(rec, base, val, off, N, NB);
    gather_k<<<(N + 3) / 4, 256, 0, stream>>>(xw, val, off, out, N);
}